// Round 8
// baseline (2280.653 us; speedup 1.0000x reference)
//
#include <hip/hip_runtime.h>
#include <hip/hip_bf16.h>

#define MAXPH 0.78539816339744831f

__device__ __forceinline__ float wsum64(float v) {
#pragma unroll
  for (int o = 32; o > 0; o >>= 1) v += __shfl_xor(v, o);
  return v;
}

// ---- prep: Wg1[j,k]=ln_g[j]*W1[j,k]; C0[k]=sum_j ln_b[j]W1[j,k]+b1[k]; G1[k]=sum_j ln_g[j]W1[j,k]
__global__ void k_prep8(const float* __restrict__ ln_g, const float* __restrict__ ln_b,
                        const float* __restrict__ w1, const float* __restrict__ b1,
                        float* __restrict__ Wg1, float* __restrict__ C0G1) {
  int t = threadIdx.x;
  for (int idx = t; idx < 128 * 32; idx += 256) {
    int j = idx >> 5;
    Wg1[idx] = ln_g[j] * w1[idx];
  }
  if (t < 32) {
    float c0 = b1[t], g1 = 0.f;
    for (int j = 0; j < 128; ++j) {
      float w = w1[j * 32 + t];
      c0 = fmaf(ln_b[j], w, c0);
      g1 = fmaf(ln_g[j], w, g1);
    }
    C0G1[t] = c0;
    C0G1[32 + t] = g1;
  }
}

// ---- per node: LN(x) -> h=xr@Wr -> mag -> S1,S2, Ad, As; self-loop initializes Cr/Sr
__global__ void k_node8(const float* __restrict__ x, const float* __restrict__ Wr,
                        const float* __restrict__ Wg1, const float* __restrict__ C0G1,
                        const float* __restrict__ w2, const float* __restrict__ b2,
                        float* __restrict__ h_out, float2* __restrict__ S12,
                        float* __restrict__ Ad, float* __restrict__ As,
                        float* __restrict__ Cr, float* __restrict__ Sr, int n) {
  __shared__ float sWr[4096];
  __shared__ float sWg1[4096];
  for (int i = threadIdx.x; i < 4096; i += blockDim.x) {
    sWr[i] = Wr[i];
    sWg1[i] = Wg1[i];
  }
  __syncthreads();
  const int lane = threadIdx.x & 63;
  const int k = lane & 31;
  const int half = lane >> 5;
  const float c0r = C0G1[k], g1r = C0G1[32 + k], w2r = w2[k], b2r = b2[0];
  const float* wg = sWg1 + half * 2048;
  const int wid = (blockIdx.x * blockDim.x + threadIdx.x) >> 6;
  const int nw = (gridDim.x * blockDim.x) >> 6;
  for (int node = wid; node < n; node += nw) {
    const float xv = x[node * 64 + lane];
    float s1 = wsum64(xv);
    float s2 = wsum64(xv * xv);
    float mean = s1 * 0.015625f;
    float var = fmaf(-mean, mean, s2 * 0.015625f);
    float rstd = rsqrtf(var + 1e-5f);
    float xr = (xv - mean) * rstd;
    float hv = 0.f;
#pragma unroll
    for (int m = 0; m < 64; ++m) hv = fmaf(__shfl(xr, m), sWr[m * 64 + lane], hv);
    float mag = sqrtf(fmaf(hv, hv, 1e-8f));
    float cm = fminf(mag, 10.f);
    float t1 = wsum64(cm);
    float t2 = wsum64(cm * cm);
    float acc = 0.f;
#pragma unroll
    for (int m = 0; m < 64; ++m) acc = fmaf(__shfl(cm, m), wg[m * 32 + k], acc);
    h_out[node * 64 + lane] = hv;
    if (half == 0) Ad[node * 32 + k] = acc;
    else           As[node * 32 + k] = acc;
    if (lane == 0) S12[node] = make_float2(t1, t2);
    // self-loop (i,i), ew=1 -> clip=1
    float meanE = t1 * 0.015625f;
    float varE = fmaf(-meanE, meanE, t2 * 0.015625f);
    float rstdE = rsqrtf(varE + 1e-5f);
    float hsum = acc + __shfl_xor(acc, 32);
    float pre = fmaf(rstdE, fmaf(-meanE, g1r, hsum), c0r);
    float contrib = fmaxf(pre, 0.f) * w2r;
    float z = fmaf(wsum64(contrib), 0.5f, b2r);
    float coup = 1.f / (1.f + expf(-z));
    float ph = fminf(0.3f * coup, MAXPH);
    float sn, cs;
    sincosf(ph, &sn, &cs);
    Cr[node * 64 + lane] = hv * cs;
    Sr[node * 64 + lane] = hv * sn;
  }
}

// ---- owner-computes aggregation (LDS accumulation; block owns dst range [lo,hi))
__global__ __launch_bounds__(256) void k_aggr8(
    const int* __restrict__ ei, const float* __restrict__ ew,
    const float2* __restrict__ S12, const float* __restrict__ Ad,
    const float* __restrict__ As, const float* __restrict__ h,
    const float* __restrict__ C0G1, const float* __restrict__ w2,
    const float* __restrict__ b2,
    float* __restrict__ Cr, float* __restrict__ Sr, int n, int ne) {
  __shared__ float tCr[4096];
  __shared__ float tSr[4096];
  const int lo = blockIdx.x << 6;
  const int hi = min(lo + 64, n);
  const int tid = threadIdx.x;
  for (int idx = tid; idx < 4096; idx += 256) {
    int r = idx >> 6;
    if (lo + r < hi) {
      tCr[idx] = Cr[(size_t)(lo + r) * 64 + (idx & 63)];
      tSr[idx] = Sr[(size_t)(lo + r) * 64 + (idx & 63)];
    }
  }
  __syncthreads();
  const int lane = tid & 63;
  const int wave = tid >> 6;
  const int k = lane & 31;
  const int half = lane >> 5;
  const float c0r = C0G1[k], g1r = C0G1[32 + k], w2r = w2[k], b2r = b2[0];
  for (int base = wave << 6; base < ne; base += 256) {
    int e = base + lane;
    int s = 0, d = -1;
    if (e < ne) {
      s = ei[e];
      d = ei[ne + e];
    }
    unsigned long long mask = __ballot(d >= lo && d < hi);
    while (mask) {
      int j = __ffsll((unsigned long long)mask) - 1;
      mask &= mask - 1;
      int e_j = base + j;
      int s_j = __shfl(s, j);
      int d_j = __shfl(d, j);
      float2 ps = S12[s_j];
      float2 pd = S12[d_j];
      float meanE = (ps.x + pd.x) * 0.0078125f;
      float varE = fmaf(-meanE, meanE, (ps.y + pd.y) * 0.0078125f);
      float rstdE = rsqrtf(varE + 1e-5f);
      float own = (half == 0) ? Ad[(size_t)d_j * 32 + k] : As[(size_t)s_j * 32 + k];
      float hsum = own + __shfl_xor(own, 32);
      float pre = fmaf(rstdE, fmaf(-meanE, g1r, hsum), c0r);
      float contrib = fmaxf(pre, 0.f) * w2r;
      float z = fmaf(wsum64(contrib), 0.5f, b2r);
      float coup = 1.f / (1.f + expf(-z));
      float cw = fminf(fmaxf(ew[e_j], 0.1f), 2.f);
      float ph = fminf(0.3f * coup * cw, MAXPH);
      float sn, cs;
      sincosf(ph, &sn, &cs);
      float hv = h[(size_t)s_j * 64 + lane];
      atomicAdd(&tCr[((d_j - lo) << 6) + lane], hv * cs);  // LDS atomic
      atomicAdd(&tSr[((d_j - lo) << 6) + lane], hv * sn);
    }
  }
  __syncthreads();
  for (int idx = tid; idx < 4096; idx += 256) {
    int r = idx >> 6;
    if (lo + r < hi) {
      Cr[(size_t)(lo + r) * 64 + (idx & 63)] = tCr[idx];
      Sr[(size_t)(lo + r) * 64 + (idx & 63)] = tSr[idx];
    }
  }
}

// ---- small graph: LDS-histogram Adj -> GCN x2 -> pool -> MLP -> B (antihermitian/32)
__global__ __launch_bounds__(1024) void k_gcnmlp8(
    const int* __restrict__ ei, int ne,
    const float* __restrict__ g1w, const float* __restrict__ g1b,
    const float* __restrict__ g2w, const float* __restrict__ g2b,
    const float* __restrict__ aw1, const float* __restrict__ ab1,
    const float* __restrict__ aw2, const float* __restrict__ ab2,
    const float* __restrict__ aw3, const float* __restrict__ ab3,
    float* __restrict__ Bg) {
  __shared__ unsigned AdjCnt[4096];
  __shared__ float L0[4096];
  __shared__ float L1[4096];
  __shared__ float L2[4096];
  __shared__ float L3[4096];
  float* dvp = L3;
  float* tsp = L3 + 64;
  float* gpp = L2;
  float* z1p = L2 + 64;
  float* z2p = L2 + 128;
  const int t = threadIdx.x;
  for (int idx = t; idx < 4096; idx += 1024) AdjCnt[idx] = 0u;
  __syncthreads();
  for (int e = t; e < ne; e += 1024) {
    int s = ei[e];
    int d = ei[ne + e];
    if ((unsigned)(s | d) < 64u) atomicAdd(&AdjCnt[d * 64 + s], 1u);
  }
  __syncthreads();
  for (int idx = t; idx < 4096; idx += 1024) L0[idx] = (float)AdjCnt[idx];
  __syncthreads();
  if (t < 64) {
    float deg = 1.f;
    for (int s2 = 0; s2 < 64; ++s2) deg += L0[t * 64 + s2];
    dvp[t] = rsqrtf(deg);
  }
  __syncthreads();
  if (t < 64) {
    float a = 0.f;
    for (int s2 = 0; s2 < 64; ++s2) a = fmaf(L0[t * 64 + s2], dvp[s2], a);
    tsp[t] = a;
  }
  __syncthreads();
  for (int idx = t; idx < 4096; idx += 1024) {
    int d = idx >> 6, kk = idx & 63;
    float v = fmaf(g1w[kk], fmaf(tsp[d], dvp[d], dvp[d] * dvp[d]), g1b[kk]);
    L1[idx] = fmaxf(v, 0.f);
  }
  __syncthreads();
  const int i = t >> 4, j0 = (t & 15) << 2;
  {  // xw = h1 @ g2w
    float a0 = 0, a1 = 0, a2 = 0, a3 = 0;
    for (int m = 0; m < 64; ++m) {
      float hm = L1[i * 64 + m];
      const float* w = g2w + m * 64 + j0;
      a0 = fmaf(hm, w[0], a0); a1 = fmaf(hm, w[1], a1);
      a2 = fmaf(hm, w[2], a2); a3 = fmaf(hm, w[3], a3);
    }
    L2[i * 64 + j0 + 0] = a0; L2[i * 64 + j0 + 1] = a1;
    L2[i * 64 + j0 + 2] = a2; L2[i * 64 + j0 + 3] = a3;
  }
  __syncthreads();
  {  // h2 = sym-norm aggregate + self term
    float a0 = 0, a1 = 0, a2 = 0, a3 = 0;
    for (int s2 = 0; s2 < 64; ++s2) {
      float w = L0[i * 64 + s2] * dvp[s2];
      const float* xr = L2 + s2 * 64 + j0;
      a0 = fmaf(w, xr[0], a0); a1 = fmaf(w, xr[1], a1);
      a2 = fmaf(w, xr[2], a2); a3 = fmaf(w, xr[3], a3);
    }
    float di = dvp[i], sc = di * di;
    const float* xs = L2 + i * 64 + j0;
    float r0 = fmaf(a0, di, fmaf(sc, xs[0], g2b[j0 + 0]));
    float r1 = fmaf(a1, di, fmaf(sc, xs[1], g2b[j0 + 1]));
    float r2 = fmaf(a2, di, fmaf(sc, xs[2], g2b[j0 + 2]));
    float r3 = fmaf(a3, di, fmaf(sc, xs[3], g2b[j0 + 3]));
    __syncthreads();
    L1[i * 64 + j0 + 0] = r0; L1[i * 64 + j0 + 1] = r1;
    L1[i * 64 + j0 + 2] = r2; L1[i * 64 + j0 + 3] = r3;
  }
  __syncthreads();
  if (t < 64) {
    float a = 0.f;
    for (int d = 0; d < 64; ++d) a += L1[d * 64 + t];
    gpp[t] = a * 0.015625f;
  }
  __syncthreads();
  if (t < 64) {
    float a = ab1[t];
    for (int m = 0; m < 64; ++m) a = fmaf(gpp[m], aw1[m * 64 + t], a);
    z1p[t] = fmaxf(a, 0.f);
  }
  __syncthreads();
  if (t < 64) {
    float a = ab2[t];
    for (int m = 0; m < 64; ++m) a = fmaf(z1p[m], aw2[m * 64 + t], a);
    z2p[t] = fmaxf(a, 0.f);
  }
  __syncthreads();
  for (int p = 0; p < 4; ++p) {
    int rc = t + p * 1024;
    float a = ab3[rc];
    for (int m = 0; m < 64; ++m) a = fmaf(z2p[m], aw3[m * 4096 + rc], a);
    L3[rc] = tanhf(a);
  }
  __syncthreads();
  const float SCC = 0.0015625f;  // 0.1 * 0.5 / 32
  for (int idx = t; idx < 4096; idx += 1024) {
    int r = idx >> 6, c = idx & 63;
    float pr = L3[r * 64 + c], pt = L3[c * 64 + r];
    Bg[idx] = (pr - pt) * SCC;
    Bg[4096 + idx] = (pr + pt) * SCC;
  }
}

// ---- expm: X = (sum_{m<=6} B^m/m!)^(2^5); write U^T (real/imag)
__global__ __launch_bounds__(1024) void k_expm8(const float* __restrict__ Bg,
                                                float* __restrict__ UrT,
                                                float* __restrict__ UiT) {
  __shared__ float A0[4096], A1[4096], B0[4096], B1[4096];
  const int t = threadIdx.x;
  const float* Brg = Bg;
  const float* Big = Bg + 4096;
  for (int idx = t; idx < 4096; idx += 1024) {
    int r = idx >> 6, c = idx & 63;
    A0[idx] = (r == c ? 1.f : 0.f) + Brg[idx] * (1.f / 6.f);
    A1[idx] = Big[idx] * (1.f / 6.f);
  }
  __syncthreads();
  float *Xr = A0, *Xi = A1, *Tr = B0, *Ti = B1;
  const int i = t >> 4, j0 = (t & 15) << 2;
  for (int kk = 5; kk >= 1; --kk) {
    float ar[4] = {0, 0, 0, 0}, ai[4] = {0, 0, 0, 0};
    const float* brr = Brg + i * 64;
    const float* bir = Big + i * 64;
    for (int m = 0; m < 64; ++m) {
      float br = brr[m], bi = bir[m];
#pragma unroll
      for (int q = 0; q < 4; ++q) {
        float xr = Xr[m * 64 + j0 + q], xi = Xi[m * 64 + j0 + q];
        ar[q] = fmaf(br, xr, fmaf(-bi, xi, ar[q]));
        ai[q] = fmaf(br, xi, fmaf(bi, xr, ai[q]));
      }
    }
    float inv = 1.f / (float)kk;
#pragma unroll
    for (int q = 0; q < 4; ++q) {
      int c = j0 + q;
      Tr[i * 64 + c] = (i == c ? 1.f : 0.f) + ar[q] * inv;
      Ti[i * 64 + c] = ai[q] * inv;
    }
    __syncthreads();
    float* tp;
    tp = Xr; Xr = Tr; Tr = tp;
    tp = Xi; Xi = Ti; Ti = tp;
  }
  for (int sq = 0; sq < 5; ++sq) {
    float ar[4] = {0, 0, 0, 0}, ai[4] = {0, 0, 0, 0};
    for (int m = 0; m < 64; ++m) {
      float br = Xr[i * 64 + m], bi = Xi[i * 64 + m];
#pragma unroll
      for (int q = 0; q < 4; ++q) {
        float xr = Xr[m * 64 + j0 + q], xi = Xi[m * 64 + j0 + q];
        ar[q] = fmaf(br, xr, fmaf(-bi, xi, ar[q]));
        ai[q] = fmaf(br, xi, fmaf(bi, xr, ai[q]));
      }
    }
#pragma unroll
    for (int q = 0; q < 4; ++q) {
      Tr[i * 64 + j0 + q] = ar[q];
      Ti[i * 64 + j0 + q] = ai[q];
    }
    __syncthreads();
    float* tp;
    tp = Xr; Xr = Tr; Tr = tp;
    tp = Xi; Xi = Ti; Ti = tp;
  }
  for (int idx = t; idx < 4096; idx += 1024) {
    int a = idx >> 6, b = idx & 63;
    UrT[idx] = Xr[b * 64 + a];
    UiT[idx] = Xi[b * 64 + a];
  }
}

// ---- final: aggr = [Cr,Sr] x U^T (complex), out = 0.5*aggr + 0.5*LN(x); f32 store
__global__ void k_final8(const float* __restrict__ x, const float* __restrict__ Cr,
                         const float* __restrict__ Sr, const float* __restrict__ UrT,
                         const float* __restrict__ UiT, float* __restrict__ out, int n) {
  __shared__ float sUr[4096], sUi[4096];
  for (int i = threadIdx.x; i < 4096; i += blockDim.x) {
    sUr[i] = UrT[i];
    sUi[i] = UiT[i];
  }
  __syncthreads();
  const int lane = threadIdx.x & 63;
  const int wid = (blockIdx.x * blockDim.x + threadIdx.x) >> 6;
  const int nw = (gridDim.x * blockDim.x) >> 6;
  const size_t imag_off = (size_t)n * 64;
  for (int node = wid; node < n; node += nw) {
    float cr = Cr[node * 64 + lane];
    float sr = Sr[node * 64 + lane];
    float ar = 0.f, ai = 0.f;
#pragma unroll
    for (int m = 0; m < 64; ++m) {
      float crm = __shfl(cr, m), srm = __shfl(sr, m);
      float ur = sUr[m * 64 + lane], ui = sUi[m * 64 + lane];
      ar = fmaf(crm, ur, fmaf(-srm, ui, ar));
      ai = fmaf(crm, ui, fmaf(srm, ur, ai));
    }
    float xv = x[node * 64 + lane];
    float s1 = wsum64(xv);
    float s2 = wsum64(xv * xv);
    float mean = s1 * 0.015625f;
    float var = fmaf(-mean, mean, s2 * 0.015625f);
    float xr = (xv - mean) * rsqrtf(var + 1e-5f);
    out[node * 64 + lane] = 0.5f * (ar + xr);          // FLOAT32 output
    out[imag_off + node * 64 + lane] = 0.5f * ai;
  }
}

extern "C" void kernel_launch(void* const* d_in, const int* in_sizes, int n_in,
                              void* d_out, int out_size, void* d_ws, size_t ws_size,
                              hipStream_t stream) {
  const float* x    = (const float*)d_in[0];
  const int*   ei   = (const int*)d_in[1];
  const float* ew   = (const float*)d_in[2];
  const float* Wr   = (const float*)d_in[3];
  const float* ln_g = (const float*)d_in[5];
  const float* ln_b = (const float*)d_in[6];
  const float* w1   = (const float*)d_in[7];
  const float* b1   = (const float*)d_in[8];
  const float* w2   = (const float*)d_in[9];
  const float* b2   = (const float*)d_in[10];
  const float* g1w  = (const float*)d_in[11];
  const float* g1b  = (const float*)d_in[12];
  const float* g2w  = (const float*)d_in[13];
  const float* g2b  = (const float*)d_in[14];
  const float* aw1  = (const float*)d_in[15];
  const float* ab1  = (const float*)d_in[16];
  const float* aw2  = (const float*)d_in[17];
  const float* ab2  = (const float*)d_in[18];
  const float* aw3  = (const float*)d_in[19];
  const float* ab3  = (const float*)d_in[20];
  const int n = in_sizes[0] / 64;
  const int e = in_sizes[1] / 2;
  float* out = (float*)d_out;  // reference output dtype is float32

  float* ws = (float*)d_ws;
  float* Wg1  = ws;                          // 4096
  float* C0G1 = ws + 4096;                   // 64
  float* UrT  = ws + 4160;                   // 4096
  float* UiT  = ws + 8256;                   // 4096
  float* Bg   = ws + 12352;                  // 8192
  float* big  = ws + 20544;
  float* Cr   = big;                                  // 64n
  float* Sr   = big + (size_t)64 * n;                 // 64n
  float2* S12 = (float2*)(big + (size_t)128 * n);     // 2n
  float* h    = big + (size_t)130 * n;                // 64n
  float* Ad   = big + (size_t)194 * n;                // 32n
  float* As   = big + (size_t)226 * n;                // 32n

  const int nb = (n + 63) >> 6;

  k_prep8<<<1, 256, 0, stream>>>(ln_g, ln_b, w1, b1, Wg1, C0G1);
  k_node8<<<1024, 256, 0, stream>>>(x, Wr, Wg1, C0G1, w2, b2, h, S12, Ad, As, Cr, Sr, n);
  k_aggr8<<<nb, 256, 0, stream>>>(ei, ew, S12, Ad, As, h, C0G1, w2, b2, Cr, Sr, n, e);
  k_gcnmlp8<<<1, 1024, 0, stream>>>(ei, e, g1w, g1b, g2w, g2b, aw1, ab1, aw2, ab2, aw3, ab3, Bg);
  k_expm8<<<1, 1024, 0, stream>>>(Bg, UrT, UiT);
  k_final8<<<1024, 256, 0, stream>>>(x, Cr, Sr, UrT, UiT, out, n);
}

// Round 9
// 1816.508 us; speedup vs baseline: 1.2555x; 1.2555x over previous
//
#include <hip/hip_runtime.h>
#include <hip/hip_bf16.h>

#define MAXPH 0.78539816339744831f

__device__ __forceinline__ float wsum64(float v) {
#pragma unroll
  for (int o = 32; o > 0; o >>= 1) v += __shfl_xor(v, o);
  return v;
}

// ---- zero CSR counters + AdjU
__global__ void k_init9(unsigned* __restrict__ AdjU, unsigned* __restrict__ cnt,
                        unsigned* __restrict__ cur, int nb) {
  int t = blockIdx.x * blockDim.x + threadIdx.x;
  int st = gridDim.x * blockDim.x;
  for (int i = t; i < 4096; i += st) AdjU[i] = 0u;
  for (int i = t; i < nb; i += st) {
    cnt[i] = 0u;
    cur[i] = 0u;
  }
}

// ---- prep: Wg1[j,k]=ln_g[j]*W1[j,k]; C0[k]; G1[k]
__global__ void k_prep9(const float* __restrict__ ln_g, const float* __restrict__ ln_b,
                        const float* __restrict__ w1, const float* __restrict__ b1,
                        float* __restrict__ Wg1, float* __restrict__ C0G1) {
  int t = threadIdx.x;
  for (int idx = t; idx < 128 * 32; idx += 256) {
    int j = idx >> 5;
    Wg1[idx] = ln_g[j] * w1[idx];
  }
  if (t < 32) {
    float c0 = b1[t], g1 = 0.f;
    for (int j = 0; j < 128; ++j) {
      float w = w1[j * 32 + t];
      c0 = fmaf(ln_b[j], w, c0);
      g1 = fmaf(ln_g[j], w, g1);
    }
    C0G1[t] = c0;
    C0G1[32 + t] = g1;
  }
}

// ---- per node: LN(x) -> h=xr@Wr -> mag -> S1,S2, Ad, As (bf16); self-loop init Cr/Sr
__global__ void k_node9(const float* __restrict__ x, const float* __restrict__ Wr,
                        const float* __restrict__ Wg1, const float* __restrict__ C0G1,
                        const float* __restrict__ w2, const float* __restrict__ b2,
                        float* __restrict__ h_out, float2* __restrict__ S12,
                        __hip_bfloat16* __restrict__ Ad, __hip_bfloat16* __restrict__ As,
                        float* __restrict__ Cr, float* __restrict__ Sr, int n) {
  __shared__ float sWr[4096];
  __shared__ float sWg1[4096];
  for (int i = threadIdx.x; i < 4096; i += blockDim.x) {
    sWr[i] = Wr[i];
    sWg1[i] = Wg1[i];
  }
  __syncthreads();
  const int lane = threadIdx.x & 63;
  const int k = lane & 31;
  const int half = lane >> 5;
  const float c0r = C0G1[k], g1r = C0G1[32 + k], w2r = w2[k], b2r = b2[0];
  const float* wg = sWg1 + half * 2048;
  const int wid = (blockIdx.x * blockDim.x + threadIdx.x) >> 6;
  const int nw = (gridDim.x * blockDim.x) >> 6;
  for (int node = wid; node < n; node += nw) {
    const float xv = x[node * 64 + lane];
    float s1 = wsum64(xv);
    float s2 = wsum64(xv * xv);
    float mean = s1 * 0.015625f;
    float var = fmaf(-mean, mean, s2 * 0.015625f);
    float rstd = rsqrtf(var + 1e-5f);
    float xr = (xv - mean) * rstd;
    float hv = 0.f;
#pragma unroll
    for (int m = 0; m < 64; ++m) hv = fmaf(__shfl(xr, m), sWr[m * 64 + lane], hv);
    float mag = sqrtf(fmaf(hv, hv, 1e-8f));
    float cm = fminf(mag, 10.f);
    float t1 = wsum64(cm);
    float t2 = wsum64(cm * cm);
    float acc = 0.f;
#pragma unroll
    for (int m = 0; m < 64; ++m) acc = fmaf(__shfl(cm, m), wg[m * 32 + k], acc);
    h_out[node * 64 + lane] = hv;
    if (half == 0) Ad[node * 32 + k] = __float2bfloat16(acc);
    else           As[node * 32 + k] = __float2bfloat16(acc);
    if (lane == 0) S12[node] = make_float2(t1, t2);
    // self-loop (i,i), ew=1 -> clip=1  (f32 acc path, matches reference closely)
    float meanE = t1 * 0.015625f;
    float varE = fmaf(-meanE, meanE, t2 * 0.015625f);
    float rstdE = rsqrtf(varE + 1e-5f);
    float hsum = acc + __shfl_xor(acc, 32);
    float pre = fmaf(rstdE, fmaf(-meanE, g1r, hsum), c0r);
    float contrib = fmaxf(pre, 0.f) * w2r;
    float z = fmaf(wsum64(contrib), 0.5f, b2r);
    float coup = 1.f / (1.f + expf(-z));
    float ph = fminf(0.3f * coup, MAXPH);
    float sn, cs;
    sincosf(ph, &sn, &cs);
    Cr[node * 64 + lane] = hv * cs;
    Sr[node * 64 + lane] = hv * sn;
  }
}

// ---- pass 1: bucket histogram by dst block + masked Adj counts
__global__ void k_count9(const int* __restrict__ ei, int ne,
                         unsigned* __restrict__ cnt, unsigned* __restrict__ AdjU) {
  int t = blockIdx.x * blockDim.x + threadIdx.x;
  int st = gridDim.x * blockDim.x;
  for (int e = t; e < ne; e += st) {
    int s = ei[e];
    int d = ei[ne + e];
    atomicAdd(&cnt[d >> 6], 1u);
    if ((unsigned)(s | d) < 64u) atomicAdd(&AdjU[d * 64 + s], 1u);
  }
}

// ---- pass 2: exclusive prefix over buckets (nb <= 4096)
__global__ __launch_bounds__(1024) void k_scan9(const unsigned* __restrict__ cnt,
                                                unsigned* __restrict__ off, int nb) {
  __shared__ unsigned sc[4097];
  int t = threadIdx.x;
  for (int i = t; i < nb; i += 1024) sc[i] = cnt[i];
  __syncthreads();
  if (t == 0) {
    unsigned acc = 0;
    for (int i = 0; i < nb; ++i) {
      unsigned c = sc[i];
      sc[i] = acc;
      acc += c;
    }
    sc[nb] = acc;
  }
  __syncthreads();
  for (int i = t; i <= nb; i += 1024) off[i] = sc[i];
}

// ---- pass 3: scatter edge ids into buckets
__global__ void k_fill9(const int* __restrict__ ei, int ne,
                        const unsigned* __restrict__ off, unsigned* __restrict__ cur,
                        int* __restrict__ eidx) {
  int t = blockIdx.x * blockDim.x + threadIdx.x;
  int st = gridDim.x * blockDim.x;
  for (int e = t; e < ne; e += st) {
    int b = ei[ne + e] >> 6;
    unsigned p = atomicAdd(&cur[b], 1u);
    eidx[off[b] + p] = e;
  }
}

// ---- aggregation: block owns dst range; lane-per-edge phase, wave-per-edge scatter
__global__ __launch_bounds__(256) void k_aggr9(
    const int* __restrict__ ei, const float* __restrict__ ew,
    const float2* __restrict__ S12,
    const __hip_bfloat16* __restrict__ Ad, const __hip_bfloat16* __restrict__ As,
    const float* __restrict__ h, const float* __restrict__ C0G1,
    const float* __restrict__ w2, const float* __restrict__ b2,
    const unsigned* __restrict__ off, const int* __restrict__ eidx,
    float* __restrict__ Cr, float* __restrict__ Sr, int n, int ne) {
  __shared__ float tCr[4096];
  __shared__ float tSr[4096];
  __shared__ float sc0[32], sg1[32], sw2[32];
  const int tid = threadIdx.x;
  if (tid < 32) {
    sc0[tid] = C0G1[tid];
    sg1[tid] = C0G1[32 + tid];
    sw2[tid] = w2[tid];
  }
  const int lo = blockIdx.x << 6;
  const int hi = min(lo + 64, n);
  for (int idx = tid; idx < 4096; idx += 256) {
    int r = idx >> 6;
    if (lo + r < hi) {
      tCr[idx] = Cr[(size_t)(lo + r) * 64 + (idx & 63)];
      tSr[idx] = Sr[(size_t)(lo + r) * 64 + (idx & 63)];
    }
  }
  __syncthreads();
  const int lane = tid & 63;
  const int wave = tid >> 6;
  const float b2r = b2[0];
  const unsigned e0 = off[blockIdx.x], e1 = off[blockIdx.x + 1];
  for (unsigned i0 = e0 + ((unsigned)wave << 6); i0 < e1; i0 += 256) {
    int cnt = (int)min(64u, e1 - i0);
    int s = 0, d = lo;
    float sn = 0.f, cs = 0.f;
    if (lane < cnt) {
      int e = eidx[i0 + lane];
      s = ei[e];
      d = ei[ne + e];
      float2 ps = S12[s];
      float2 pd = S12[d];
      float meanE = (ps.x + pd.x) * 0.0078125f;
      float varE = fmaf(-meanE, meanE, (ps.y + pd.y) * 0.0078125f);
      float rstdE = rsqrtf(varE + 1e-5f);
      const uint4* adq = (const uint4*)(Ad + (size_t)d * 32);
      const uint4* asq = (const uint4*)(As + (size_t)s * 32);
      float z = b2r;
#pragma unroll
      for (int q = 0; q < 4; ++q) {
        uint4 ua = adq[q];
        uint4 ub = asq[q];
        unsigned av[4] = {ua.x, ua.y, ua.z, ua.w};
        unsigned bv[4] = {ub.x, ub.y, ub.z, ub.w};
#pragma unroll
        for (int p = 0; p < 4; ++p) {
          int k0 = q * 8 + p * 2;
          float a0 = __uint_as_float(av[p] << 16);
          float a1 = __uint_as_float(av[p] & 0xFFFF0000u);
          float b0 = __uint_as_float(bv[p] << 16);
          float b1 = __uint_as_float(bv[p] & 0xFFFF0000u);
          float pre0 = fmaf(rstdE, fmaf(-meanE, sg1[k0], a0 + b0), sc0[k0]);
          float pre1 = fmaf(rstdE, fmaf(-meanE, sg1[k0 + 1], a1 + b1), sc0[k0 + 1]);
          z = fmaf(fmaxf(pre0, 0.f), sw2[k0], z);
          z = fmaf(fmaxf(pre1, 0.f), sw2[k0 + 1], z);
        }
      }
      float coup = 1.f / (1.f + expf(-z));
      float cw = fminf(fmaxf(ew[e], 0.1f), 2.f);
      float ph = fminf(0.3f * coup * cw, MAXPH);
      sincosf(ph, &sn, &cs);
    }
    for (int j = 0; j < cnt; ++j) {
      int s_j = __shfl(s, j);
      int d_j = __shfl(d, j);
      float cs_j = __shfl(cs, j);
      float sn_j = __shfl(sn, j);
      float hv = h[(size_t)s_j * 64 + lane];
      atomicAdd(&tCr[((d_j - lo) << 6) + lane], hv * cs_j);
      atomicAdd(&tSr[((d_j - lo) << 6) + lane], hv * sn_j);
    }
  }
  __syncthreads();
  for (int idx = tid; idx < 4096; idx += 256) {
    int r = idx >> 6;
    if (lo + r < hi) {
      Cr[(size_t)(lo + r) * 64 + (idx & 63)] = tCr[idx];
      Sr[(size_t)(lo + r) * 64 + (idx & 63)] = tSr[idx];
    }
  }
}

// ---- small graph: AdjU (prebuilt) -> GCN x2 -> pool -> MLP -> B (antihermitian/32)
__global__ __launch_bounds__(1024) void k_gcnmlp9(
    const unsigned* __restrict__ AdjU,
    const float* __restrict__ g1w, const float* __restrict__ g1b,
    const float* __restrict__ g2w, const float* __restrict__ g2b,
    const float* __restrict__ aw1, const float* __restrict__ ab1,
    const float* __restrict__ aw2, const float* __restrict__ ab2,
    const float* __restrict__ aw3, const float* __restrict__ ab3,
    float* __restrict__ Bg) {
  __shared__ float L0[4096];
  __shared__ float L1[4096];
  __shared__ float L2[4096];
  __shared__ float L3[4096];
  float* dvp = L3;
  float* tsp = L3 + 64;
  float* gpp = L2;
  float* z1p = L2 + 64;
  float* z2p = L2 + 128;
  const int t = threadIdx.x;
  for (int idx = t; idx < 4096; idx += 1024) L0[idx] = (float)AdjU[idx];
  __syncthreads();
  if (t < 64) {
    float deg = 1.f;
    for (int s2 = 0; s2 < 64; ++s2) deg += L0[t * 64 + s2];
    dvp[t] = rsqrtf(deg);
  }
  __syncthreads();
  if (t < 64) {
    float a = 0.f;
    for (int s2 = 0; s2 < 64; ++s2) a = fmaf(L0[t * 64 + s2], dvp[s2], a);
    tsp[t] = a;
  }
  __syncthreads();
  for (int idx = t; idx < 4096; idx += 1024) {
    int d = idx >> 6, kk = idx & 63;
    float v = fmaf(g1w[kk], fmaf(tsp[d], dvp[d], dvp[d] * dvp[d]), g1b[kk]);
    L1[idx] = fmaxf(v, 0.f);
  }
  __syncthreads();
  const int i = t >> 4, j0 = (t & 15) << 2;
  {  // xw = h1 @ g2w
    float a0 = 0, a1 = 0, a2 = 0, a3 = 0;
    for (int m = 0; m < 64; ++m) {
      float hm = L1[i * 64 + m];
      const float* w = g2w + m * 64 + j0;
      a0 = fmaf(hm, w[0], a0); a1 = fmaf(hm, w[1], a1);
      a2 = fmaf(hm, w[2], a2); a3 = fmaf(hm, w[3], a3);
    }
    L2[i * 64 + j0 + 0] = a0; L2[i * 64 + j0 + 1] = a1;
    L2[i * 64 + j0 + 2] = a2; L2[i * 64 + j0 + 3] = a3;
  }
  __syncthreads();
  {  // h2 = sym-norm aggregate + self term
    float a0 = 0, a1 = 0, a2 = 0, a3 = 0;
    for (int s2 = 0; s2 < 64; ++s2) {
      float w = L0[i * 64 + s2] * dvp[s2];
      const float* xr = L2 + s2 * 64 + j0;
      a0 = fmaf(w, xr[0], a0); a1 = fmaf(w, xr[1], a1);
      a2 = fmaf(w, xr[2], a2); a3 = fmaf(w, xr[3], a3);
    }
    float di = dvp[i], sc = di * di;
    const float* xs = L2 + i * 64 + j0;
    float r0 = fmaf(a0, di, fmaf(sc, xs[0], g2b[j0 + 0]));
    float r1 = fmaf(a1, di, fmaf(sc, xs[1], g2b[j0 + 1]));
    float r2 = fmaf(a2, di, fmaf(sc, xs[2], g2b[j0 + 2]));
    float r3 = fmaf(a3, di, fmaf(sc, xs[3], g2b[j0 + 3]));
    __syncthreads();
    L1[i * 64 + j0 + 0] = r0; L1[i * 64 + j0 + 1] = r1;
    L1[i * 64 + j0 + 2] = r2; L1[i * 64 + j0 + 3] = r3;
  }
  __syncthreads();
  if (t < 64) {
    float a = 0.f;
    for (int d = 0; d < 64; ++d) a += L1[d * 64 + t];
    gpp[t] = a * 0.015625f;
  }
  __syncthreads();
  if (t < 64) {
    float a = ab1[t];
    for (int m = 0; m < 64; ++m) a = fmaf(gpp[m], aw1[m * 64 + t], a);
    z1p[t] = fmaxf(a, 0.f);
  }
  __syncthreads();
  if (t < 64) {
    float a = ab2[t];
    for (int m = 0; m < 64; ++m) a = fmaf(z1p[m], aw2[m * 64 + t], a);
    z2p[t] = fmaxf(a, 0.f);
  }
  __syncthreads();
  for (int p = 0; p < 4; ++p) {
    int rc = t + p * 1024;
    float a = ab3[rc];
    for (int m = 0; m < 64; ++m) a = fmaf(z2p[m], aw3[m * 4096 + rc], a);
    L3[rc] = tanhf(a);
  }
  __syncthreads();
  const float SCC = 0.0015625f;  // 0.1 * 0.5 / 32
  for (int idx = t; idx < 4096; idx += 1024) {
    int r = idx >> 6, c = idx & 63;
    float pr = L3[r * 64 + c], pt = L3[c * 64 + r];
    Bg[idx] = (pr - pt) * SCC;
    Bg[4096 + idx] = (pr + pt) * SCC;
  }
}

// ---- expm: X = (sum_{m<=6} B^m/m!)^(2^5); write U^T
__global__ __launch_bounds__(1024) void k_expm9(const float* __restrict__ Bg,
                                                float* __restrict__ UrT,
                                                float* __restrict__ UiT) {
  __shared__ float A0[4096], A1[4096], B0[4096], B1[4096];
  const int t = threadIdx.x;
  const float* Brg = Bg;
  const float* Big = Bg + 4096;
  for (int idx = t; idx < 4096; idx += 1024) {
    int r = idx >> 6, c = idx & 63;
    A0[idx] = (r == c ? 1.f : 0.f) + Brg[idx] * (1.f / 6.f);
    A1[idx] = Big[idx] * (1.f / 6.f);
  }
  __syncthreads();
  float *Xr = A0, *Xi = A1, *Tr = B0, *Ti = B1;
  const int i = t >> 4, j0 = (t & 15) << 2;
  for (int kk = 5; kk >= 1; --kk) {
    float ar[4] = {0, 0, 0, 0}, ai[4] = {0, 0, 0, 0};
    const float* brr = Brg + i * 64;
    const float* bir = Big + i * 64;
    for (int m = 0; m < 64; ++m) {
      float br = brr[m], bi = bir[m];
#pragma unroll
      for (int q = 0; q < 4; ++q) {
        float xr = Xr[m * 64 + j0 + q], xi = Xi[m * 64 + j0 + q];
        ar[q] = fmaf(br, xr, fmaf(-bi, xi, ar[q]));
        ai[q] = fmaf(br, xi, fmaf(bi, xr, ai[q]));
      }
    }
    float inv = 1.f / (float)kk;
#pragma unroll
    for (int q = 0; q < 4; ++q) {
      int c = j0 + q;
      Tr[i * 64 + c] = (i == c ? 1.f : 0.f) + ar[q] * inv;
      Ti[i * 64 + c] = ai[q] * inv;
    }
    __syncthreads();
    float* tp;
    tp = Xr; Xr = Tr; Tr = tp;
    tp = Xi; Xi = Ti; Ti = tp;
  }
  for (int sq = 0; sq < 5; ++sq) {
    float ar[4] = {0, 0, 0, 0}, ai[4] = {0, 0, 0, 0};
    for (int m = 0; m < 64; ++m) {
      float br = Xr[i * 64 + m], bi = Xi[i * 64 + m];
#pragma unroll
      for (int q = 0; q < 4; ++q) {
        float xr = Xr[m * 64 + j0 + q], xi = Xi[m * 64 + j0 + q];
        ar[q] = fmaf(br, xr, fmaf(-bi, xi, ar[q]));
        ai[q] = fmaf(br, xi, fmaf(bi, xr, ai[q]));
      }
    }
#pragma unroll
    for (int q = 0; q < 4; ++q) {
      Tr[i * 64 + j0 + q] = ar[q];
      Ti[i * 64 + j0 + q] = ai[q];
    }
    __syncthreads();
    float* tp;
    tp = Xr; Xr = Tr; Tr = tp;
    tp = Xi; Xi = Ti; Ti = tp;
  }
  for (int idx = t; idx < 4096; idx += 1024) {
    int a = idx >> 6, b = idx & 63;
    UrT[idx] = Xr[b * 64 + a];
    UiT[idx] = Xi[b * 64 + a];
  }
}

// ---- final: aggr = [Cr,Sr] x U^T (complex), out = 0.5*aggr + 0.5*LN(x); f32 store
__global__ void k_final9(const float* __restrict__ x, const float* __restrict__ Cr,
                         const float* __restrict__ Sr, const float* __restrict__ UrT,
                         const float* __restrict__ UiT, float* __restrict__ out, int n) {
  __shared__ float sUr[4096], sUi[4096];
  for (int i = threadIdx.x; i < 4096; i += blockDim.x) {
    sUr[i] = UrT[i];
    sUi[i] = UiT[i];
  }
  __syncthreads();
  const int lane = threadIdx.x & 63;
  const int wid = (blockIdx.x * blockDim.x + threadIdx.x) >> 6;
  const int nw = (gridDim.x * blockDim.x) >> 6;
  const size_t imag_off = (size_t)n * 64;
  for (int node = wid; node < n; node += nw) {
    float cr = Cr[node * 64 + lane];
    float sr = Sr[node * 64 + lane];
    float ar = 0.f, ai = 0.f;
#pragma unroll
    for (int m = 0; m < 64; ++m) {
      float crm = __shfl(cr, m), srm = __shfl(sr, m);
      float ur = sUr[m * 64 + lane], ui = sUi[m * 64 + lane];
      ar = fmaf(crm, ur, fmaf(-srm, ui, ar));
      ai = fmaf(crm, ui, fmaf(srm, ur, ai));
    }
    float xv = x[node * 64 + lane];
    float s1 = wsum64(xv);
    float s2 = wsum64(xv * xv);
    float mean = s1 * 0.015625f;
    float var = fmaf(-mean, mean, s2 * 0.015625f);
    float xr = (xv - mean) * rsqrtf(var + 1e-5f);
    out[node * 64 + lane] = 0.5f * (ar + xr);
    out[imag_off + node * 64 + lane] = 0.5f * ai;
  }
}

extern "C" void kernel_launch(void* const* d_in, const int* in_sizes, int n_in,
                              void* d_out, int out_size, void* d_ws, size_t ws_size,
                              hipStream_t stream) {
  const float* x    = (const float*)d_in[0];
  const int*   ei   = (const int*)d_in[1];
  const float* ew   = (const float*)d_in[2];
  const float* Wr   = (const float*)d_in[3];
  const float* ln_g = (const float*)d_in[5];
  const float* ln_b = (const float*)d_in[6];
  const float* w1   = (const float*)d_in[7];
  const float* b1   = (const float*)d_in[8];
  const float* w2   = (const float*)d_in[9];
  const float* b2   = (const float*)d_in[10];
  const float* g1w  = (const float*)d_in[11];
  const float* g1b  = (const float*)d_in[12];
  const float* g2w  = (const float*)d_in[13];
  const float* g2b  = (const float*)d_in[14];
  const float* aw1  = (const float*)d_in[15];
  const float* ab1  = (const float*)d_in[16];
  const float* aw2  = (const float*)d_in[17];
  const float* ab2  = (const float*)d_in[18];
  const float* aw3  = (const float*)d_in[19];
  const float* ab3  = (const float*)d_in[20];
  const int n = in_sizes[0] / 64;
  const int e = in_sizes[1] / 2;
  const int nb = (n + 63) >> 6;
  float* out = (float*)d_out;

  float* ws = (float*)d_ws;
  float* Wg1  = ws;                          // 4096
  float* C0G1 = ws + 4096;                   // 64
  float* UrT  = ws + 4160;                   // 4096
  float* UiT  = ws + 8256;                   // 4096
  float* Bg   = ws + 12352;                  // 8192
  // int region
  unsigned* AdjU = (unsigned*)(ws + 20544);  // 4096
  unsigned* cnt  = AdjU + 4096;              // nb
  unsigned* off  = cnt + nb;                 // nb+1
  unsigned* cur  = off + nb + 1;             // nb
  int* eidx      = (int*)(cur + nb);         // e
  size_t int_end = 20544 + 4096 + 3 * (size_t)nb + 1 + (size_t)e;
  size_t bigofs  = (int_end + 63) & ~(size_t)63;
  float* big = ws + bigofs;
  float* Cr   = big;                                     // 64n
  float* Sr   = big + (size_t)64 * n;                    // 64n
  float* h    = big + (size_t)128 * n;                   // 64n
  float2* S12 = (float2*)(big + (size_t)192 * n);        // 2n
  __hip_bfloat16* Ad = (__hip_bfloat16*)(big + (size_t)194 * n);  // 16n f32-equiv
  __hip_bfloat16* As = (__hip_bfloat16*)(big + (size_t)210 * n);  // 16n f32-equiv

  k_init9<<<8, 256, 0, stream>>>(AdjU, cnt, cur, nb);
  k_prep9<<<1, 256, 0, stream>>>(ln_g, ln_b, w1, b1, Wg1, C0G1);
  k_node9<<<1024, 256, 0, stream>>>(x, Wr, Wg1, C0G1, w2, b2, h, S12, Ad, As, Cr, Sr, n);
  k_count9<<<1024, 256, 0, stream>>>(ei, e, cnt, AdjU);
  k_scan9<<<1, 1024, 0, stream>>>(cnt, off, nb);
  k_fill9<<<1024, 256, 0, stream>>>(ei, e, off, cur, eidx);
  k_aggr9<<<nb, 256, 0, stream>>>(ei, ew, S12, Ad, As, h, C0G1, w2, b2, off, eidx, Cr, Sr, n, e);
  k_gcnmlp9<<<1, 1024, 0, stream>>>(AdjU, g1w, g1b, g2w, g2b, aw1, ab1, aw2, ab2, aw3, ab3, Bg);
  k_expm9<<<1, 1024, 0, stream>>>(Bg, UrT, UiT);
  k_final9<<<1024, 256, 0, stream>>>(x, Cr, Sr, UrT, UiT, out, n);
}

// Round 10
// 1416.802 us; speedup vs baseline: 1.6097x; 1.2821x over previous
//
#include <hip/hip_runtime.h>
#include <hip/hip_bf16.h>

#define MAXPH 0.78539816339744831f

__device__ __forceinline__ float wsum64(float v) {
#pragma unroll
  for (int o = 32; o > 0; o >>= 1) v += __shfl_xor(v, o);
  return v;
}

// ---- zero bucket counters + AdjU
__global__ void k_init10(unsigned* __restrict__ AdjU, unsigned* __restrict__ cnt, int nb) {
  int t = blockIdx.x * blockDim.x + threadIdx.x;
  int st = gridDim.x * blockDim.x;
  for (int i = t; i < 4096; i += st) AdjU[i] = 0u;
  for (int i = t; i < nb; i += st) cnt[i] = 0u;
}

// ---- prep: Wg1[j,k]=ln_g[j]*W1[j,k]; C0[k]; G1[k]
__global__ void k_prep10(const float* __restrict__ ln_g, const float* __restrict__ ln_b,
                         const float* __restrict__ w1, const float* __restrict__ b1,
                         float* __restrict__ Wg1, float* __restrict__ C0G1) {
  int t = threadIdx.x;
  for (int idx = t; idx < 128 * 32; idx += 256) {
    int j = idx >> 5;
    Wg1[idx] = ln_g[j] * w1[idx];
  }
  if (t < 32) {
    float c0 = b1[t], g1 = 0.f;
    for (int j = 0; j < 128; ++j) {
      float w = w1[j * 32 + t];
      c0 = fmaf(ln_b[j], w, c0);
      g1 = fmaf(ln_g[j], w, g1);
    }
    C0G1[t] = c0;
    C0G1[32 + t] = g1;
  }
}

// ---- per node: LN(x) -> h=xr@Wr (bf16 out) -> mag -> S1,S2, Ad, As (bf16); self-loop init Cr/Sr
__global__ void k_node10(const float* __restrict__ x, const float* __restrict__ Wr,
                         const float* __restrict__ Wg1, const float* __restrict__ C0G1,
                         const float* __restrict__ w2, const float* __restrict__ b2,
                         __hip_bfloat16* __restrict__ h_out, float2* __restrict__ S12,
                         __hip_bfloat16* __restrict__ Ad, __hip_bfloat16* __restrict__ As,
                         float* __restrict__ Cr, float* __restrict__ Sr, int n) {
  __shared__ float sWr[4096];
  __shared__ float sWg1[4096];
  for (int i = threadIdx.x; i < 4096; i += blockDim.x) {
    sWr[i] = Wr[i];
    sWg1[i] = Wg1[i];
  }
  __syncthreads();
  const int lane = threadIdx.x & 63;
  const int k = lane & 31;
  const int half = lane >> 5;
  const float c0r = C0G1[k], g1r = C0G1[32 + k], w2r = w2[k], b2r = b2[0];
  const float* wg = sWg1 + half * 2048;
  const int wid = (blockIdx.x * blockDim.x + threadIdx.x) >> 6;
  const int nw = (gridDim.x * blockDim.x) >> 6;
  for (int node = wid; node < n; node += nw) {
    const float xv = x[node * 64 + lane];
    float s1 = wsum64(xv);
    float s2 = wsum64(xv * xv);
    float mean = s1 * 0.015625f;
    float var = fmaf(-mean, mean, s2 * 0.015625f);
    float rstd = rsqrtf(var + 1e-5f);
    float xr = (xv - mean) * rstd;
    float hv = 0.f;
#pragma unroll
    for (int m = 0; m < 64; ++m) hv = fmaf(__shfl(xr, m), sWr[m * 64 + lane], hv);
    float mag = sqrtf(fmaf(hv, hv, 1e-8f));
    float cm = fminf(mag, 10.f);
    float t1 = wsum64(cm);
    float t2 = wsum64(cm * cm);
    float acc = 0.f;
#pragma unroll
    for (int m = 0; m < 64; ++m) acc = fmaf(__shfl(cm, m), wg[m * 32 + k], acc);
    h_out[node * 64 + lane] = __float2bfloat16(hv);
    if (half == 0) Ad[node * 32 + k] = __float2bfloat16(acc);
    else           As[node * 32 + k] = __float2bfloat16(acc);
    if (lane == 0) S12[node] = make_float2(t1, t2);
    // self-loop (i,i), ew=1 -> clip=1 (full f32 path)
    float meanE = t1 * 0.015625f;
    float varE = fmaf(-meanE, meanE, t2 * 0.015625f);
    float rstdE = rsqrtf(varE + 1e-5f);
    float hsum = acc + __shfl_xor(acc, 32);
    float pre = fmaf(rstdE, fmaf(-meanE, g1r, hsum), c0r);
    float contrib = fmaxf(pre, 0.f) * w2r;
    float z = fmaf(wsum64(contrib), 0.5f, b2r);
    float coup = 1.f / (1.f + expf(-z));
    float ph = fminf(0.3f * coup, MAXPH);
    float sn, cs;
    sincosf(ph, &sn, &cs);
    Cr[node * 64 + lane] = hv * cs;
    Sr[node * 64 + lane] = hv * sn;
  }
}

// ---- single-pass bucketing: histogram + packed edge records + AdjU
//      record: { s | (d&31)<<25 , ew_bits } ; bucket = d>>5, fixed capacity
__global__ void k_fill10(const int* __restrict__ ei, const float* __restrict__ ew, int ne,
                         unsigned* __restrict__ cnt, unsigned* __restrict__ AdjU,
                         int2* __restrict__ eb, int cap) {
  int t = blockIdx.x * blockDim.x + threadIdx.x;
  int st = gridDim.x * blockDim.x;
  for (int e = t; e < ne; e += st) {
    int s = ei[e];
    int d = ei[ne + e];
    if ((unsigned)(s | d) < 64u) atomicAdd(&AdjU[d * 64 + s], 1u);
    int b = d >> 5;
    unsigned p = atomicAdd(&cnt[b], 1u);
    if (p < (unsigned)cap)
      eb[(size_t)b * cap + p] = make_int2(s | ((d & 31) << 25), __float_as_int(ew[e]));
  }
}

// ---- aggregation: block owns 32 dst nodes; lane-per-edge phase, wave-per-edge scatter
__global__ __launch_bounds__(256) void k_aggr10(
    const int2* __restrict__ eb, const unsigned* __restrict__ cnt, int cap,
    const float2* __restrict__ S12,
    const __hip_bfloat16* __restrict__ Ad, const __hip_bfloat16* __restrict__ As,
    const __hip_bfloat16* __restrict__ hbf, const float* __restrict__ C0G1,
    const float* __restrict__ w2, const float* __restrict__ b2,
    float* __restrict__ Cr, float* __restrict__ Sr, int n) {
  __shared__ float tCr[2048];
  __shared__ float tSr[2048];
  __shared__ float sc0[32], sg1[32], sw2[32];
  const int tid = threadIdx.x;
  if (tid < 32) {
    sc0[tid] = C0G1[tid];
    sg1[tid] = C0G1[32 + tid];
    sw2[tid] = w2[tid];
  }
  const int lo = blockIdx.x << 5;
  const int rows = min(32, n - lo);
  for (int idx = tid; idx < 2048; idx += 256) {
    int r = idx >> 6;
    if (r < rows) {
      tCr[idx] = Cr[(size_t)(lo + r) * 64 + (idx & 63)];
      tSr[idx] = Sr[(size_t)(lo + r) * 64 + (idx & 63)];
    }
  }
  __syncthreads();
  const int lane = tid & 63;
  const int wave = tid >> 6;
  const float b2r = b2[0];
  const unsigned nEdge = min(cnt[blockIdx.x], (unsigned)cap);
  const size_t base = (size_t)blockIdx.x * cap;
  for (unsigned i0 = (unsigned)wave << 6; i0 < nEdge; i0 += 256) {
    int cnt64 = (int)min(64u, nEdge - i0);
    int s = 0, dloc = 0;
    float sn = 0.f, cs = 0.f;
    if (lane < cnt64) {
      int2 rec = eb[base + i0 + lane];
      s = rec.x & 0x1FFFFFF;
      dloc = (rec.x >> 25) & 31;
      int d = lo + dloc;
      float2 ps = S12[s];
      float2 pd = S12[d];
      float meanE = (ps.x + pd.x) * 0.0078125f;
      float varE = fmaf(-meanE, meanE, (ps.y + pd.y) * 0.0078125f);
      float rstdE = rsqrtf(varE + 1e-5f);
      const uint4* adq = (const uint4*)(Ad + (size_t)d * 32);
      const uint4* asq = (const uint4*)(As + (size_t)s * 32);
      float z = b2r;
#pragma unroll
      for (int q = 0; q < 4; ++q) {
        uint4 ua = adq[q];
        uint4 ub = asq[q];
        unsigned av[4] = {ua.x, ua.y, ua.z, ua.w};
        unsigned bv[4] = {ub.x, ub.y, ub.z, ub.w};
#pragma unroll
        for (int p = 0; p < 4; ++p) {
          int k0 = q * 8 + p * 2;
          float a0 = __uint_as_float(av[p] << 16);
          float a1 = __uint_as_float(av[p] & 0xFFFF0000u);
          float b0 = __uint_as_float(bv[p] << 16);
          float b1 = __uint_as_float(bv[p] & 0xFFFF0000u);
          float pre0 = fmaf(rstdE, fmaf(-meanE, sg1[k0], a0 + b0), sc0[k0]);
          float pre1 = fmaf(rstdE, fmaf(-meanE, sg1[k0 + 1], a1 + b1), sc0[k0 + 1]);
          z = fmaf(fmaxf(pre0, 0.f), sw2[k0], z);
          z = fmaf(fmaxf(pre1, 0.f), sw2[k0 + 1], z);
        }
      }
      float coup = 1.f / (1.f + expf(-z));
      float cw = fminf(fmaxf(__int_as_float(rec.y), 0.1f), 2.f);
      float ph = fminf(0.3f * coup * cw, MAXPH);
      sincosf(ph, &sn, &cs);
    }
    int j = 0;
    for (; j + 1 < cnt64; j += 2) {
      int s0 = __shfl(s, j), d0 = __shfl(dloc, j);
      float c0 = __shfl(cs, j), n0 = __shfl(sn, j);
      int s1 = __shfl(s, j + 1), d1 = __shfl(dloc, j + 1);
      float c1 = __shfl(cs, j + 1), n1 = __shfl(sn, j + 1);
      float h0 = __bfloat162float(hbf[(size_t)s0 * 64 + lane]);
      float h1 = __bfloat162float(hbf[(size_t)s1 * 64 + lane]);
      atomicAdd(&tCr[(d0 << 6) + lane], h0 * c0);
      atomicAdd(&tSr[(d0 << 6) + lane], h0 * n0);
      atomicAdd(&tCr[(d1 << 6) + lane], h1 * c1);
      atomicAdd(&tSr[(d1 << 6) + lane], h1 * n1);
    }
    if (j < cnt64) {
      int s0 = __shfl(s, j), d0 = __shfl(dloc, j);
      float c0 = __shfl(cs, j), n0 = __shfl(sn, j);
      float h0 = __bfloat162float(hbf[(size_t)s0 * 64 + lane]);
      atomicAdd(&tCr[(d0 << 6) + lane], h0 * c0);
      atomicAdd(&tSr[(d0 << 6) + lane], h0 * n0);
    }
  }
  __syncthreads();
  for (int idx = tid; idx < 2048; idx += 256) {
    int r = idx >> 6;
    if (r < rows) {
      Cr[(size_t)(lo + r) * 64 + (idx & 63)] = tCr[idx];
      Sr[(size_t)(lo + r) * 64 + (idx & 63)] = tSr[idx];
    }
  }
}

// ---- small graph: AdjU -> GCN x2 -> pool -> MLP -> B (antihermitian/32)
__global__ __launch_bounds__(1024) void k_gcnmlp10(
    const unsigned* __restrict__ AdjU,
    const float* __restrict__ g1w, const float* __restrict__ g1b,
    const float* __restrict__ g2w, const float* __restrict__ g2b,
    const float* __restrict__ aw1, const float* __restrict__ ab1,
    const float* __restrict__ aw2, const float* __restrict__ ab2,
    const float* __restrict__ aw3, const float* __restrict__ ab3,
    float* __restrict__ Bg) {
  __shared__ float L0[4096];
  __shared__ float L1[4096];
  __shared__ float L2[4096];
  __shared__ float L3[4096];
  float* dvp = L3;
  float* tsp = L3 + 64;
  float* gpp = L2;
  float* z1p = L2 + 64;
  float* z2p = L2 + 128;
  const int t = threadIdx.x;
  for (int idx = t; idx < 4096; idx += 1024) L0[idx] = (float)AdjU[idx];
  __syncthreads();
  if (t < 64) {
    float deg = 1.f;
    for (int s2 = 0; s2 < 64; ++s2) deg += L0[t * 64 + s2];
    dvp[t] = rsqrtf(deg);
  }
  __syncthreads();
  if (t < 64) {
    float a = 0.f;
    for (int s2 = 0; s2 < 64; ++s2) a = fmaf(L0[t * 64 + s2], dvp[s2], a);
    tsp[t] = a;
  }
  __syncthreads();
  for (int idx = t; idx < 4096; idx += 1024) {
    int d = idx >> 6, kk = idx & 63;
    float v = fmaf(g1w[kk], fmaf(tsp[d], dvp[d], dvp[d] * dvp[d]), g1b[kk]);
    L1[idx] = fmaxf(v, 0.f);
  }
  __syncthreads();
  const int i = t >> 4, j0 = (t & 15) << 2;
  {  // xw = h1 @ g2w
    float a0 = 0, a1 = 0, a2 = 0, a3 = 0;
    for (int m = 0; m < 64; ++m) {
      float hm = L1[i * 64 + m];
      const float* w = g2w + m * 64 + j0;
      a0 = fmaf(hm, w[0], a0); a1 = fmaf(hm, w[1], a1);
      a2 = fmaf(hm, w[2], a2); a3 = fmaf(hm, w[3], a3);
    }
    L2[i * 64 + j0 + 0] = a0; L2[i * 64 + j0 + 1] = a1;
    L2[i * 64 + j0 + 2] = a2; L2[i * 64 + j0 + 3] = a3;
  }
  __syncthreads();
  {  // h2 = sym-norm aggregate + self term
    float a0 = 0, a1 = 0, a2 = 0, a3 = 0;
    for (int s2 = 0; s2 < 64; ++s2) {
      float w = L0[i * 64 + s2] * dvp[s2];
      const float* xr = L2 + s2 * 64 + j0;
      a0 = fmaf(w, xr[0], a0); a1 = fmaf(w, xr[1], a1);
      a2 = fmaf(w, xr[2], a2); a3 = fmaf(w, xr[3], a3);
    }
    float di = dvp[i], sc = di * di;
    const float* xs = L2 + i * 64 + j0;
    float r0 = fmaf(a0, di, fmaf(sc, xs[0], g2b[j0 + 0]));
    float r1 = fmaf(a1, di, fmaf(sc, xs[1], g2b[j0 + 1]));
    float r2 = fmaf(a2, di, fmaf(sc, xs[2], g2b[j0 + 2]));
    float r3 = fmaf(a3, di, fmaf(sc, xs[3], g2b[j0 + 3]));
    __syncthreads();
    L1[i * 64 + j0 + 0] = r0; L1[i * 64 + j0 + 1] = r1;
    L1[i * 64 + j0 + 2] = r2; L1[i * 64 + j0 + 3] = r3;
  }
  __syncthreads();
  if (t < 64) {
    float a = 0.f;
    for (int d = 0; d < 64; ++d) a += L1[d * 64 + t];
    gpp[t] = a * 0.015625f;
  }
  __syncthreads();
  if (t < 64) {
    float a = ab1[t];
    for (int m = 0; m < 64; ++m) a = fmaf(gpp[m], aw1[m * 64 + t], a);
    z1p[t] = fmaxf(a, 0.f);
  }
  __syncthreads();
  if (t < 64) {
    float a = ab2[t];
    for (int m = 0; m < 64; ++m) a = fmaf(z1p[m], aw2[m * 64 + t], a);
    z2p[t] = fmaxf(a, 0.f);
  }
  __syncthreads();
  for (int p = 0; p < 4; ++p) {
    int rc = t + p * 1024;
    float a = ab3[rc];
    for (int m = 0; m < 64; ++m) a = fmaf(z2p[m], aw3[m * 4096 + rc], a);
    L3[rc] = tanhf(a);
  }
  __syncthreads();
  const float SCC = 0.0015625f;  // 0.1 * 0.5 / 32
  for (int idx = t; idx < 4096; idx += 1024) {
    int r = idx >> 6, c = idx & 63;
    float pr = L3[r * 64 + c], pt = L3[c * 64 + r];
    Bg[idx] = (pr - pt) * SCC;
    Bg[4096 + idx] = (pr + pt) * SCC;
  }
}

// ---- expm: X = (sum_{m<=6} B^m/m!)^(2^5); write U^T
__global__ __launch_bounds__(1024) void k_expm10(const float* __restrict__ Bg,
                                                 float* __restrict__ UrT,
                                                 float* __restrict__ UiT) {
  __shared__ float A0[4096], A1[4096], B0[4096], B1[4096];
  const int t = threadIdx.x;
  const float* Brg = Bg;
  const float* Big = Bg + 4096;
  for (int idx = t; idx < 4096; idx += 1024) {
    int r = idx >> 6, c = idx & 63;
    A0[idx] = (r == c ? 1.f : 0.f) + Brg[idx] * (1.f / 6.f);
    A1[idx] = Big[idx] * (1.f / 6.f);
  }
  __syncthreads();
  float *Xr = A0, *Xi = A1, *Tr = B0, *Ti = B1;
  const int i = t >> 4, j0 = (t & 15) << 2;
  for (int kk = 5; kk >= 1; --kk) {
    float ar[4] = {0, 0, 0, 0}, ai[4] = {0, 0, 0, 0};
    const float* brr = Brg + i * 64;
    const float* bir = Big + i * 64;
    for (int m = 0; m < 64; ++m) {
      float br = brr[m], bi = bir[m];
#pragma unroll
      for (int q = 0; q < 4; ++q) {
        float xr = Xr[m * 64 + j0 + q], xi = Xi[m * 64 + j0 + q];
        ar[q] = fmaf(br, xr, fmaf(-bi, xi, ar[q]));
        ai[q] = fmaf(br, xi, fmaf(bi, xr, ai[q]));
      }
    }
    float inv = 1.f / (float)kk;
#pragma unroll
    for (int q = 0; q < 4; ++q) {
      int c = j0 + q;
      Tr[i * 64 + c] = (i == c ? 1.f : 0.f) + ar[q] * inv;
      Ti[i * 64 + c] = ai[q] * inv;
    }
    __syncthreads();
    float* tp;
    tp = Xr; Xr = Tr; Tr = tp;
    tp = Xi; Xi = Ti; Ti = tp;
  }
  for (int sq = 0; sq < 5; ++sq) {
    float ar[4] = {0, 0, 0, 0}, ai[4] = {0, 0, 0, 0};
    for (int m = 0; m < 64; ++m) {
      float br = Xr[i * 64 + m], bi = Xi[i * 64 + m];
#pragma unroll
      for (int q = 0; q < 4; ++q) {
        float xr = Xr[m * 64 + j0 + q], xi = Xi[m * 64 + j0 + q];
        ar[q] = fmaf(br, xr, fmaf(-bi, xi, ar[q]));
        ai[q] = fmaf(br, xi, fmaf(bi, xr, ai[q]));
      }
    }
#pragma unroll
    for (int q = 0; q < 4; ++q) {
      Tr[i * 64 + j0 + q] = ar[q];
      Ti[i * 64 + j0 + q] = ai[q];
    }
    __syncthreads();
    float* tp;
    tp = Xr; Xr = Tr; Tr = tp;
    tp = Xi; Xi = Ti; Ti = tp;
  }
  for (int idx = t; idx < 4096; idx += 1024) {
    int a = idx >> 6, b = idx & 63;
    UrT[idx] = Xr[b * 64 + a];
    UiT[idx] = Xi[b * 64 + a];
  }
}

// ---- final: aggr = [Cr,Sr] x U^T (complex), out = 0.5*aggr + 0.5*LN(x); f32 store
__global__ void k_final10(const float* __restrict__ x, const float* __restrict__ Cr,
                          const float* __restrict__ Sr, const float* __restrict__ UrT,
                          const float* __restrict__ UiT, float* __restrict__ out, int n) {
  __shared__ float sUr[4096], sUi[4096];
  for (int i = threadIdx.x; i < 4096; i += blockDim.x) {
    sUr[i] = UrT[i];
    sUi[i] = UiT[i];
  }
  __syncthreads();
  const int lane = threadIdx.x & 63;
  const int wid = (blockIdx.x * blockDim.x + threadIdx.x) >> 6;
  const int nw = (gridDim.x * blockDim.x) >> 6;
  const size_t imag_off = (size_t)n * 64;
  for (int node = wid; node < n; node += nw) {
    float cr = Cr[node * 64 + lane];
    float sr = Sr[node * 64 + lane];
    float ar = 0.f, ai = 0.f;
#pragma unroll
    for (int m = 0; m < 64; ++m) {
      float crm = __shfl(cr, m), srm = __shfl(sr, m);
      float ur = sUr[m * 64 + lane], ui = sUi[m * 64 + lane];
      ar = fmaf(crm, ur, fmaf(-srm, ui, ar));
      ai = fmaf(crm, ui, fmaf(srm, ur, ai));
    }
    float xv = x[node * 64 + lane];
    float s1 = wsum64(xv);
    float s2 = wsum64(xv * xv);
    float mean = s1 * 0.015625f;
    float var = fmaf(-mean, mean, s2 * 0.015625f);
    float xr = (xv - mean) * rsqrtf(var + 1e-5f);
    out[node * 64 + lane] = 0.5f * (ar + xr);
    out[imag_off + node * 64 + lane] = 0.5f * ai;
  }
}

extern "C" void kernel_launch(void* const* d_in, const int* in_sizes, int n_in,
                              void* d_out, int out_size, void* d_ws, size_t ws_size,
                              hipStream_t stream) {
  const float* x    = (const float*)d_in[0];
  const int*   ei   = (const int*)d_in[1];
  const float* ew   = (const float*)d_in[2];
  const float* Wr   = (const float*)d_in[3];
  const float* ln_g = (const float*)d_in[5];
  const float* ln_b = (const float*)d_in[6];
  const float* w1   = (const float*)d_in[7];
  const float* b1   = (const float*)d_in[8];
  const float* w2   = (const float*)d_in[9];
  const float* b2   = (const float*)d_in[10];
  const float* g1w  = (const float*)d_in[11];
  const float* g1b  = (const float*)d_in[12];
  const float* g2w  = (const float*)d_in[13];
  const float* g2b  = (const float*)d_in[14];
  const float* aw1  = (const float*)d_in[15];
  const float* ab1  = (const float*)d_in[16];
  const float* aw2  = (const float*)d_in[17];
  const float* ab2  = (const float*)d_in[18];
  const float* aw3  = (const float*)d_in[19];
  const float* ab3  = (const float*)d_in[20];
  const int n = in_sizes[0] / 64;
  const int e = in_sizes[1] / 2;
  const int nb = (n + 31) >> 5;               // 32-node buckets
  const int cap = ((e + nb - 1) / nb) * 3 / 2 + 64;
  float* out = (float*)d_out;

  float* ws = (float*)d_ws;
  float* Wg1  = ws;                           // 4096
  float* C0G1 = ws + 4096;                    // 64
  float* UrT  = ws + 4160;                    // 4096
  float* UiT  = ws + 8256;                    // 4096
  float* Bg   = ws + 12352;                   // 8192
  unsigned* AdjU = (unsigned*)(ws + 20544);   // 4096 u32
  unsigned* cnt  = AdjU + 4096;               // nb u32
  size_t ebofs = (20544 + 4096 + (size_t)nb + 63) & ~(size_t)63;
  int2* eb = (int2*)(ws + ebofs);             // nb*cap int2
  size_t bigofs = (ebofs + 2 * (size_t)nb * cap + 63) & ~(size_t)63;
  float* big = ws + bigofs;
  float* Cr   = big;                                      // 64n f32
  float* Sr   = big + (size_t)64 * n;                     // 64n f32
  float2* S12 = (float2*)(big + (size_t)128 * n);         // 2n f32
  __hip_bfloat16* h  = (__hip_bfloat16*)(big + (size_t)130 * n);  // 32n f32-equiv
  __hip_bfloat16* Ad = (__hip_bfloat16*)(big + (size_t)162 * n);  // 16n
  __hip_bfloat16* As = (__hip_bfloat16*)(big + (size_t)178 * n);  // 16n

  k_init10<<<8, 256, 0, stream>>>(AdjU, cnt, nb);
  k_prep10<<<1, 256, 0, stream>>>(ln_g, ln_b, w1, b1, Wg1, C0G1);
  k_node10<<<1024, 256, 0, stream>>>(x, Wr, Wg1, C0G1, w2, b2, h, S12, Ad, As, Cr, Sr, n);
  k_fill10<<<1024, 256, 0, stream>>>(ei, ew, e, cnt, AdjU, eb, cap);
  k_aggr10<<<nb, 256, 0, stream>>>(eb, cnt, cap, S12, Ad, As, h, C0G1, w2, b2, Cr, Sr, n);
  k_gcnmlp10<<<1, 1024, 0, stream>>>(AdjU, g1w, g1b, g2w, g2b, aw1, ab1, aw2, ab2, aw3, ab3, Bg);
  k_expm10<<<1, 1024, 0, stream>>>(Bg, UrT, UiT);
  k_final10<<<1024, 256, 0, stream>>>(x, Cr, Sr, UrT, UiT, out, n);
}